// Round 17
// baseline (663.077 us; speedup 1.0000x reference)
//
#include <hip/hip_runtime.h>

typedef __attribute__((ext_vector_type(8))) short short8;
typedef __attribute__((ext_vector_type(4))) float floatx4;
typedef __attribute__((ext_vector_type(2))) unsigned int uintx2;
typedef __attribute__((ext_vector_type(4))) unsigned int uintx4;
typedef unsigned short u16;

#define MFMA(a, b, c) __builtin_amdgcn_mfma_f32_16x16x32_bf16((a), (b), (c), 0, 0, 0)
#define BAR() do { asm volatile("" ::: "memory"); __builtin_amdgcn_s_barrier(); \
                   asm volatile("" ::: "memory"); } while (0)
#define LGKM0() asm volatile("s_waitcnt lgkmcnt(0)" ::: "memory")
#define LGKM8() asm volatile("s_waitcnt lgkmcnt(8)" ::: "memory")

__device__ __forceinline__ u16 f2bf(float f) {
  unsigned int u = __builtin_bit_cast(unsigned int, f);
  u += ((u >> 16) & 1u) + 0x7fffu;
  return (u16)(u >> 16);
}

__device__ __forceinline__ float softplus_f(float v) {
  float a = __builtin_fabsf(v);
  float e = __expf(-a);
  float l = __logf(1.0f + e);
  return __builtin_fmaxf(v, 0.0f) + l;
}

__device__ __forceinline__ unsigned int pack_sp(float lo, float hi) {
  return (unsigned int)f2bf(softplus_f(lo)) | ((unsigned int)f2bf(softplus_f(hi)) << 16);
}

// out[n*K + k] = bf16(in[k*N + n]); in is K x N row-major fp32
__global__ void transpose_cvt(const float* __restrict__ in, u16* __restrict__ out, int K, int N) {
  __shared__ float tile[32][33];
  const int bn = blockIdx.x * 32, bk = blockIdx.y * 32;
  const int tx = threadIdx.x, ty = threadIdx.y;  // 32 x 8
#pragma unroll
  for (int i = 0; i < 32; i += 8)
    tile[ty + i][tx] = in[(size_t)(bk + ty + i) * N + bn + tx];
  __syncthreads();
#pragma unroll
  for (int i = 0; i < 32; i += 8)
    out[(size_t)(bn + ty + i) * K + bk + tx] = f2bf(tile[tx][ty + i]);
}

__device__ __forceinline__ void gld16(const void* g, void* l) {
  __builtin_amdgcn_global_load_lds((const __attribute__((address_space(1))) void*)g,
                                   (__attribute__((address_space(3))) void*)l, 16, 0, 0);
}

template <int LN>
__device__ __forceinline__ void vwait() {
  if constexpr (LN == 0) asm volatile("s_waitcnt vmcnt(0)" ::: "memory");
  else if constexpr (LN == 4) asm volatile("s_waitcnt vmcnt(4)" ::: "memory");
  else if constexpr (LN == 8) asm volatile("s_waitcnt vmcnt(8)" ::: "memory");
}

// ===== Persistent 128x128 GEMM (C = act @ wt^T), BK=64 double-burst, =====
// ===== NT consecutive bm-tiles per block at fixed bn; pipeline runs    =====
// ===== continuously across tile boundaries; epilogue in the off-parity =====
// ===== 32KB buffer (in-flight loads always target the other buffer).   =====
// Window (R16-verified): {stage(u+1) -> vwait -> BAR -> 8 reads k0 + 8 reads
// k1 -> lgkmcnt(8) -> 16 MFMA -> lgkmcnt(0) -> 16 MFMA -> BAR}.
// Half layout: granule (r,q) at slot r*8 + (q ^ (r&7)); kc=1 = kc=0 ^ 32.
template <int K, int EPI, bool ACTF32, int NT>
__global__ __launch_bounds__(256, 2) void gemmp(const void* __restrict__ actv,
                                                const u16* __restrict__ wt,
                                                void* __restrict__ Cout, int N, int nbn) {
  constexpr int H = K / 64;
  constexpr int LOG2H = (H == 4 ? 2 : 4);
  static_assert(H == 4 || H == 16, "H must be 4 or 16");
  constexpr int NW = NT * H;  // total windows
  constexpr int BUF = 16384;  // u16: A 8192 + W 8192 (32 KB); x2 = 64 KB
  __shared__ u16 lds[2 * BUF];
  u16* L = lds;
  const int tid = threadIdx.x, lane = tid & 63, wv = tid >> 6;  // 4 waves
  const int l15 = lane & 15, g = lane >> 4;
  const int wvm = wv >> 1, wvn = wv & 1;  // 2 x 2; wave owns 64m x 64n
  const int nwg = gridDim.x, o = blockIdx.x;
  const int sw = (o & 7) * (nwg >> 3) + (o >> 3);  // XCD swizzle (nwg % 8 == 0)
  const int bm0 = (sw / nbn) * NT, bn = sw % nbn;
  const size_t wn0 = (size_t)bn * 128;

  // fragment offsets for kc=0 (u16 units within a buffer); kc=1 = ^32
  int afo[4], wfo[4];
#pragma unroll
  for (int mt = 0; mt < 4; ++mt) {
    const int r = wvm * 64 + mt * 16 + l15;
    afo[mt] = (r * 8 + (g ^ (r & 7))) * 8;
  }
#pragma unroll
  for (int nt = 0; nt < 4; ++nt) {
    const int r = wvn * 64 + nt * 16 + l15;
    wfo[nt] = 8192 + (r * 8 + (g ^ (r & 7))) * 8;
  }

  // staging: thread fills slots s = j*256 + tid (j=0..3); granule (s>>3, (s&7)^(r&7))
  int rS[4], qS[4];
#pragma unroll
  for (int j = 0; j < 4; ++j) {
    const int s = j * 256 + tid;
    rS[j] = s >> 3;
    qS[j] = (s & 7) ^ (rS[j] & 7);
  }
  const u16* asrc = nullptr;
  const float* fsrc = nullptr;
  if constexpr (ACTF32) fsrc = (const float*)actv + (size_t)bm0 * 128 * K;
  else asrc = (const u16*)actv + (size_t)bm0 * 128 * K;
  const u16* wsrc = wt + wn0 * K;

  // stage window uu (tile uu>>LOG2H, k-window uu&(H-1)) into buffer (uu&1)
#define STG_W(uu)                                                                   \
  { const int h_ = (uu) & (H - 1);                                                  \
    _Pragma("unroll") for (int j = 0; j < 4; ++j)                                   \
      gld16(wsrc + (size_t)rS[j] * K + qS[j] * 8 + h_ * 64,                         \
            L + ((uu) & 1) * BUF + 8192 + (j * 256 + tid) * 8); }
#define STG_AB(uu)                                                                  \
  { const int h_ = (uu) & (H - 1);                                                  \
    const size_t tb_ = (size_t)((uu) >> LOG2H) * 128 * K;                           \
    _Pragma("unroll") for (int j = 0; j < 4; ++j)                                   \
      gld16(asrc + tb_ + (size_t)rS[j] * K + qS[j] * 8 + h_ * 64,                   \
            L + ((uu) & 1) * BUF + (j * 256 + tid) * 8); }
#define STG_AF(uu)                                                                  \
  { const int h_ = (uu) & (H - 1);                                                  \
    const size_t tb_ = (size_t)((uu) >> LOG2H) * 128 * K;                           \
    floatx4 v0[4], v1[4];                                                           \
    _Pragma("unroll") for (int j = 0; j < 4; ++j) {                                 \
      const float* p_ = fsrc + tb_ + (size_t)rS[j] * K + qS[j] * 8 + h_ * 64;       \
      v0[j] = *(const floatx4*)p_;                                                  \
      v1[j] = *(const floatx4*)(p_ + 4);                                            \
    }                                                                               \
    _Pragma("unroll") for (int j = 0; j < 4; ++j) {                                 \
      uintx4 w_;                                                                    \
      w_.x = (unsigned)f2bf(v0[j].x) | ((unsigned)f2bf(v0[j].y) << 16);             \
      w_.y = (unsigned)f2bf(v0[j].z) | ((unsigned)f2bf(v0[j].w) << 16);             \
      w_.z = (unsigned)f2bf(v1[j].x) | ((unsigned)f2bf(v1[j].y) << 16);             \
      w_.w = (unsigned)f2bf(v1[j].z) | ((unsigned)f2bf(v1[j].w) << 16);             \
      *(uintx4*)(L + ((uu) & 1) * BUF + (j * 256 + tid) * 8) = w_;                  \
    } }

  floatx4 acc[4][4];
  const floatx4 z4 = {0.f, 0.f, 0.f, 0.f};
#pragma unroll
  for (int nt = 0; nt < 4; ++nt)
#pragma unroll
    for (int mt = 0; mt < 4; ++mt) acc[nt][mt] = z4;

  // prologue: stage window 0
  if constexpr (ACTF32) { STG_W(0) STG_AF(0) }
  else { STG_AB(0) STG_W(0) }

#pragma unroll 1
  for (int u = 0; u < NW; ++u) {
    const int cb = (u & 1) * BUF;
    if (u + 1 < NW) {
      if constexpr (ACTF32) { STG_W(u + 1) STG_AF(u + 1) LGKM0(); vwait<4>(); }
      else { STG_AB(u + 1) STG_W(u + 1) vwait<8>(); }
    } else {
      if constexpr (ACTF32) LGKM0();
      vwait<0>();
    }
    BAR();
    short8 a0 = *(const short8*)(L + cb + afo[0]);
    short8 a1 = *(const short8*)(L + cb + afo[1]);
    short8 a2 = *(const short8*)(L + cb + afo[2]);
    short8 a3 = *(const short8*)(L + cb + afo[3]);
    short8 w0 = *(const short8*)(L + cb + wfo[0]);
    short8 w1 = *(const short8*)(L + cb + wfo[1]);
    short8 w2 = *(const short8*)(L + cb + wfo[2]);
    short8 w3 = *(const short8*)(L + cb + wfo[3]);
    short8 b0 = *(const short8*)(L + cb + (afo[0] ^ 32));
    short8 b1 = *(const short8*)(L + cb + (afo[1] ^ 32));
    short8 b2 = *(const short8*)(L + cb + (afo[2] ^ 32));
    short8 b3 = *(const short8*)(L + cb + (afo[3] ^ 32));
    short8 x0 = *(const short8*)(L + cb + (wfo[0] ^ 32));
    short8 x1 = *(const short8*)(L + cb + (wfo[1] ^ 32));
    short8 x2 = *(const short8*)(L + cb + (wfo[2] ^ 32));
    short8 x3 = *(const short8*)(L + cb + (wfo[3] ^ 32));
    LGKM8();
    __builtin_amdgcn_s_setprio(1);
    acc[0][0] = MFMA(w0, a0, acc[0][0]);
    acc[0][1] = MFMA(w0, a1, acc[0][1]);
    acc[0][2] = MFMA(w0, a2, acc[0][2]);
    acc[0][3] = MFMA(w0, a3, acc[0][3]);
    acc[1][0] = MFMA(w1, a0, acc[1][0]);
    acc[1][1] = MFMA(w1, a1, acc[1][1]);
    acc[1][2] = MFMA(w1, a2, acc[1][2]);
    acc[1][3] = MFMA(w1, a3, acc[1][3]);
    acc[2][0] = MFMA(w2, a0, acc[2][0]);
    acc[2][1] = MFMA(w2, a1, acc[2][1]);
    acc[2][2] = MFMA(w2, a2, acc[2][2]);
    acc[2][3] = MFMA(w2, a3, acc[2][3]);
    acc[3][0] = MFMA(w3, a0, acc[3][0]);
    acc[3][1] = MFMA(w3, a1, acc[3][1]);
    acc[3][2] = MFMA(w3, a2, acc[3][2]);
    acc[3][3] = MFMA(w3, a3, acc[3][3]);
    LGKM0();
    acc[0][0] = MFMA(x0, b0, acc[0][0]);
    acc[0][1] = MFMA(x0, b1, acc[0][1]);
    acc[0][2] = MFMA(x0, b2, acc[0][2]);
    acc[0][3] = MFMA(x0, b3, acc[0][3]);
    acc[1][0] = MFMA(x1, b0, acc[1][0]);
    acc[1][1] = MFMA(x1, b1, acc[1][1]);
    acc[1][2] = MFMA(x1, b2, acc[1][2]);
    acc[1][3] = MFMA(x1, b3, acc[1][3]);
    acc[2][0] = MFMA(x2, b0, acc[2][0]);
    acc[2][1] = MFMA(x2, b1, acc[2][1]);
    acc[2][2] = MFMA(x2, b2, acc[2][2]);
    acc[2][3] = MFMA(x2, b3, acc[2][3]);
    acc[3][0] = MFMA(x3, b0, acc[3][0]);
    acc[3][1] = MFMA(x3, b1, acc[3][1]);
    acc[3][2] = MFMA(x3, b2, acc[3][2]);
    acc[3][3] = MFMA(x3, b3, acc[3][3]);
    __builtin_amdgcn_s_setprio(0);
    BAR();

    // ---- tile boundary: epilogue in the off-parity buffer ----
    // In-flight loads (window u+1) target buffer (u+1)&1; scratch = buffer (u&1).
    if ((u & (H - 1)) == H - 1) {
      const size_t am0 = (size_t)(bm0 + (u >> LOG2H)) * 128;
      u16* scr = L + cb;  // 32 KB, safe: not a gld16 target while in flight
      if constexpr (EPI == 0) {
        u16* cl = scr;
#pragma unroll
        for (int nt = 0; nt < 4; ++nt)
#pragma unroll
          for (int mt = 0; mt < 4; ++mt) {
            const int m = wvm * 64 + mt * 16 + l15;
            const int n0 = wvn * 64 + nt * 16 + g * 4;
            const int j = n0 >> 3, hh = (n0 >> 2) & 1;
            uintx2 pk;
            pk.x = pack_sp(acc[nt][mt].x, acc[nt][mt].y);
            pk.y = pack_sp(acc[nt][mt].z, acc[nt][mt].w);
            *(uintx2*)(cl + m * 128 + ((j ^ (m & 7)) << 3) + (hh << 2)) = pk;
          }
        __syncthreads();
        u16* outp = (u16*)Cout;
#pragma unroll
        for (int i = 0; i < 8; ++i) {
          const int c = i * 256 + tid;  // 16B chunk; 16/row, 128 rows
          const int m = c >> 4, j = c & 15;
          uintx4 v = *(const uintx4*)(cl + m * 128 + ((j ^ (m & 7)) << 3));
          *(uintx4*)(outp + (am0 + m) * N + wn0 + j * 8) = v;
        }
        __syncthreads();
      } else {
        float* cf = (float*)scr;  // 64 rows x 128 f32 = 32 KB per pass
#pragma unroll
        for (int q = 0; q < 2; ++q) {
          if (q) __syncthreads();
          if (wvm == q) {
#pragma unroll
            for (int nt = 0; nt < 4; ++nt)
#pragma unroll
              for (int mt = 0; mt < 4; ++mt) {
                const int m = mt * 16 + l15;  // 0..63
                const int p = (wvn * 64 + nt * 16 + g * 4) >> 1;
                *(floatx4*)(cf + m * 128 + ((p ^ ((m & 7) << 1)) << 1)) = acc[nt][mt];
              }
          }
          __syncthreads();
          float* outp = (float*)Cout;
#pragma unroll
          for (int i = 0; i < 8; ++i) {
            const int c = i * 256 + tid;  // 16B chunk; 32/row, 64 rows
            const int m = c >> 5, cc = c & 31;
            const int p = cc * 2;
            floatx4 v = *(const floatx4*)(cf + m * 128 + ((p ^ ((m & 7) << 1)) << 1));
            *(floatx4*)(outp + (am0 + q * 64 + m) * N + wn0 + cc * 4) = v;
          }
        }
        __syncthreads();
      }
      if (u + 1 < NW) {
#pragma unroll
        for (int nt = 0; nt < 4; ++nt)
#pragma unroll
          for (int mt = 0; mt < 4; ++mt) acc[nt][mt] = z4;
      }
    }
  }
#undef STG_W
#undef STG_AB
#undef STG_AF
}

// ---------------- fallback: R1 fused kernel (ws too small) ----------------
__global__ __launch_bounds__(512, 2) void mlp3_fused(const float* __restrict__ x,
                                                     const u16* __restrict__ w1t,
                                                     const u16* __restrict__ w2t,
                                                     const u16* __restrict__ w3t,
                                                     float* __restrict__ out) {
  __shared__ u16 h1s[64 * 1024];
  __shared__ u16 xs[64 * 256];
  const int tid = threadIdx.x, lane = tid & 63, wv = tid >> 6;
  const int l15 = lane & 15, g = lane >> 4;
  const size_t m0 = (size_t)blockIdx.x * 64;
  const floatx4 z4 = {0.f, 0.f, 0.f, 0.f};
  {
    const float* xp = x + m0 * 256;
#pragma unroll
    for (int r = 0; r < 8; ++r) {
      int idx4 = r * 512 + tid;
      int m = idx4 >> 6, k = (idx4 & 63) << 2;
      floatx4 v = *(const floatx4*)(xp + m * 256 + k);
      uintx2 pk;
      pk.x = (unsigned)f2bf(v.x) | ((unsigned)f2bf(v.y) << 16);
      pk.y = (unsigned)f2bf(v.z) | ((unsigned)f2bf(v.w) << 16);
      *(uintx2*)(xs + ((m * 256 + k) ^ ((m & 7) << 3))) = pk;
    }
  }
  __syncthreads();
#pragma unroll 1
  for (int c = 0; c < 4; ++c) {
    floatx4 acc[2][4];
#pragma unroll
    for (int t = 0; t < 2; ++t)
#pragma unroll
      for (int mt = 0; mt < 4; ++mt) acc[t][mt] = z4;
    const u16* p0 = w1t + (size_t)(c * 256 + wv * 32 + l15) * 256;
#pragma unroll
    for (int ks = 0; ks < 8; ++ks) {
      const int k = ks * 32 + g * 8;
      short8 a0 = *(const short8*)(p0 + k);
      short8 a1 = *(const short8*)(p0 + 16 * 256 + k);
      short8 b0 = *(const short8*)(xs + (((0 * 16 + l15) * 256 + k) ^ ((l15 & 7) << 3)));
      short8 b1 = *(const short8*)(xs + (((1 * 16 + l15) * 256 + k) ^ ((l15 & 7) << 3)));
      short8 b2 = *(const short8*)(xs + (((2 * 16 + l15) * 256 + k) ^ ((l15 & 7) << 3)));
      short8 b3 = *(const short8*)(xs + (((3 * 16 + l15) * 256 + k) ^ ((l15 & 7) << 3)));
      acc[0][0] = MFMA(a0, b0, acc[0][0]); acc[0][1] = MFMA(a0, b1, acc[0][1]);
      acc[0][2] = MFMA(a0, b2, acc[0][2]); acc[0][3] = MFMA(a0, b3, acc[0][3]);
      acc[1][0] = MFMA(a1, b0, acc[1][0]); acc[1][1] = MFMA(a1, b1, acc[1][1]);
      acc[1][2] = MFMA(a1, b2, acc[1][2]); acc[1][3] = MFMA(a1, b3, acc[1][3]);
    }
#pragma unroll
    for (int t = 0; t < 2; ++t)
#pragma unroll
      for (int mt = 0; mt < 4; ++mt) {
        const int n1 = c * 256 + wv * 32 + t * 16 + g * 4;
        const int m = mt * 16 + l15;
        uintx2 pk;
        pk.x = pack_sp(acc[t][mt].x, acc[t][mt].y);
        pk.y = pack_sp(acc[t][mt].z, acc[t][mt].w);
        *(uintx2*)(h1s + ((m * 1024 + n1) ^ ((m & 7) << 3))) = pk;
      }
  }
  __syncthreads();
  floatx4 acc3[2][4];
#pragma unroll
  for (int t = 0; t < 2; ++t)
#pragma unroll
    for (int mt = 0; mt < 4; ++mt) acc3[t][mt] = z4;
#pragma unroll 1
  for (int c2 = 0; c2 < 4; ++c2) {
    floatx4 acc2[2][4];
#pragma unroll
    for (int t = 0; t < 2; ++t)
#pragma unroll
      for (int mt = 0; mt < 4; ++mt) acc2[t][mt] = z4;
    {
      const u16* p0 = w2t + (size_t)(c2 * 256 + wv * 32 + l15) * 1024;
#pragma unroll 4
      for (int ks = 0; ks < 32; ++ks) {
        const int k = ks * 32 + g * 8;
        short8 a0 = *(const short8*)(p0 + k);
        short8 a1 = *(const short8*)(p0 + 16 * 1024 + k);
        short8 b0 = *(const short8*)(h1s + (((0 * 16 + l15) * 1024 + k) ^ ((l15 & 7) << 3)));
        short8 b1 = *(const short8*)(h1s + (((1 * 16 + l15) * 1024 + k) ^ ((l15 & 7) << 3)));
        short8 b2 = *(const short8*)(h1s + (((2 * 16 + l15) * 1024 + k) ^ ((l15 & 7) << 3)));
        short8 b3 = *(const short8*)(h1s + (((3 * 16 + l15) * 1024 + k) ^ ((l15 & 7) << 3)));
        acc2[0][0] = MFMA(a0, b0, acc2[0][0]); acc2[0][1] = MFMA(a0, b1, acc2[0][1]);
        acc2[0][2] = MFMA(a0, b2, acc2[0][2]); acc2[0][3] = MFMA(a0, b3, acc2[0][3]);
        acc2[1][0] = MFMA(a1, b0, acc2[1][0]); acc2[1][1] = MFMA(a1, b1, acc2[1][1]);
        acc2[1][2] = MFMA(a1, b2, acc2[1][2]); acc2[1][3] = MFMA(a1, b3, acc2[1][3]);
      }
    }
    __syncthreads();
#pragma unroll
    for (int t = 0; t < 2; ++t)
#pragma unroll
      for (int mt = 0; mt < 4; ++mt) {
        const int n2l = wv * 32 + t * 16 + g * 4;
        const int m = mt * 16 + l15;
        uintx2 pk;
        pk.x = pack_sp(acc2[t][mt].x, acc2[t][mt].y);
        pk.y = pack_sp(acc2[t][mt].z, acc2[t][mt].w);
        *(uintx2*)(xs + ((m * 256 + n2l) ^ ((m & 7) << 3))) = pk;
      }
    __syncthreads();
    {
      const u16* p0 = w3t + (size_t)(wv * 32 + l15) * 1024 + c2 * 256;
#pragma unroll
      for (int ks = 0; ks < 8; ++ks) {
        const int k = ks * 32 + g * 8;
        short8 a0 = *(const short8*)(p0 + k);
        short8 a1 = *(const short8*)(p0 + 16 * 1024 + k);
        short8 b0 = *(const short8*)(xs + (((0 * 16 + l15) * 256 + k) ^ ((l15 & 7) << 3)));
        short8 b1 = *(const short8*)(xs + (((1 * 16 + l15) * 256 + k) ^ ((l15 & 7) << 3)));
        short8 b2 = *(const short8*)(xs + (((2 * 16 + l15) * 256 + k) ^ ((l15 & 7) << 3)));
        short8 b3 = *(const short8*)(xs + (((3 * 16 + l15) * 256 + k) ^ ((l15 & 7) << 3)));
        acc3[0][0] = MFMA(a0, b0, acc3[0][0]); acc3[0][1] = MFMA(a0, b1, acc3[0][1]);
        acc3[0][2] = MFMA(a0, b2, acc3[0][2]); acc3[0][3] = MFMA(a0, b3, acc3[0][3]);
        acc3[1][0] = MFMA(a1, b0, acc3[1][0]); acc3[1][1] = MFMA(a1, b1, acc3[1][1]);
        acc3[1][2] = MFMA(a1, b2, acc3[1][2]); acc3[1][3] = MFMA(a1, b3, acc3[1][3]);
      }
    }
  }
#pragma unroll
  for (int t = 0; t < 2; ++t)
#pragma unroll
    for (int mt = 0; mt < 4; ++mt) {
      const int n3 = wv * 32 + t * 16 + g * 4;
      const int m = mt * 16 + l15;
      *(floatx4*)(out + (m0 + m) * 256 + n3) = acc3[t][mt];
    }
}

extern "C" void kernel_launch(void* const* d_in, const int* in_sizes, int n_in,
                              void* d_out, int out_size, void* d_ws, size_t ws_size,
                              hipStream_t stream) {
  const float* x = (const float*)d_in[0];
  const float* w1 = (const float*)d_in[1];
  const float* w2 = (const float*)d_in[2];
  const float* w3 = (const float*)d_in[3];
  float* out = (float*)d_out;
  const size_t M = 131072;

  u16* w1t = (u16*)d_ws;                      // [1024][256]
  u16* w2t = w1t + 1024 * 256;                // [1024][1024]
  u16* w3t = w2t + 1024 * 1024;               // [256][1024]
  u16* bufA = w3t + 256 * 1024;               // h1: CM x 1024 bf16
  const size_t weights_el = 1024 * 256 + 1024 * 1024 + 256 * 1024;

  size_t CM = 0;
  const size_t cands[4] = {32768, 16384, 8192, 4096};
  for (int i = 0; i < 4; ++i) {
    size_t need = (weights_el + 2 * cands[i] * 1024) * sizeof(u16);
    if (ws_size >= need) { CM = cands[i]; break; }
  }

  dim3 tb(32, 8);
  transpose_cvt<<<dim3(32, 8), tb, 0, stream>>>(w1, w1t, 256, 1024);
  transpose_cvt<<<dim3(32, 32), tb, 0, stream>>>(w2, w2t, 1024, 1024);
  transpose_cvt<<<dim3(8, 32), tb, 0, stream>>>(w3, w3t, 1024, 256);

  if (CM >= 32768) {
    u16* bufB = bufA + CM * 1024;
    const int nchunk = (int)(M / CM);
    for (int ci = 0; ci < nchunk; ++ci) {
      const float* xc = x + (size_t)ci * CM * 256;
      float* oc = out + (size_t)ci * CM * 256;
      // grids: (CM/128/NT)*nbn, all %8==0 at CM=32768
      gemmp<256, 0, true, 4><<<(int)(CM / 512) * 8, 256, 0, stream>>>(xc, w1t, bufA, 1024, 8);
      gemmp<1024, 0, false, 4><<<(int)(CM / 512) * 8, 256, 0, stream>>>(bufA, w2t, bufB, 1024, 8);
      gemmp<1024, 1, false, 1><<<(int)(CM / 128) * 2, 256, 0, stream>>>(bufB, w3t, oc, 256, 2);
    }
  } else if (CM) {
    u16* bufB = bufA + CM * 1024;
    const int nchunk = (int)(M / CM);
    for (int ci = 0; ci < nchunk; ++ci) {
      const float* xc = x + (size_t)ci * CM * 256;
      float* oc = out + (size_t)ci * CM * 256;
      gemmp<256, 0, true, 1><<<(int)(CM / 128) * 8, 256, 0, stream>>>(xc, w1t, bufA, 1024, 8);
      gemmp<1024, 0, false, 1><<<(int)(CM / 128) * 8, 256, 0, stream>>>(bufA, w2t, bufB, 1024, 8);
      gemmp<1024, 1, false, 1><<<(int)(CM / 128) * 2, 256, 0, stream>>>(bufB, w3t, oc, 256, 2);
    }
  } else {
    mlp3_fused<<<M / 64, 512, 0, stream>>>(x, w1t, w2t, w3t, out);
  }
}

// Round 18
// 630.335 us; speedup vs baseline: 1.0519x; 1.0519x over previous
//
#include <hip/hip_runtime.h>

typedef __attribute__((ext_vector_type(8))) short short8;
typedef __attribute__((ext_vector_type(4))) float floatx4;
typedef __attribute__((ext_vector_type(2))) unsigned int uintx2;
typedef __attribute__((ext_vector_type(4))) unsigned int uintx4;
typedef unsigned short u16;

#define MFMA(a, b, c) __builtin_amdgcn_mfma_f32_16x16x32_bf16((a), (b), (c), 0, 0, 0)
#define BAR() do { asm volatile("" ::: "memory"); __builtin_amdgcn_s_barrier(); \
                   asm volatile("" ::: "memory"); } while (0)
#define LGKM0() asm volatile("s_waitcnt lgkmcnt(0)" ::: "memory")
#define LGKM8() asm volatile("s_waitcnt lgkmcnt(8)" ::: "memory")

__device__ __forceinline__ u16 f2bf(float f) {
  unsigned int u = __builtin_bit_cast(unsigned int, f);
  u += ((u >> 16) & 1u) + 0x7fffu;
  return (u16)(u >> 16);
}

__device__ __forceinline__ float softplus_f(float v) {
  float a = __builtin_fabsf(v);
  float e = __expf(-a);
  float l = __logf(1.0f + e);
  return __builtin_fmaxf(v, 0.0f) + l;
}

__device__ __forceinline__ unsigned int pack_sp(float lo, float hi) {
  return (unsigned int)f2bf(softplus_f(lo)) | ((unsigned int)f2bf(softplus_f(hi)) << 16);
}

// out[n*K + k] = bf16(in[k*N + n]); in is K x N row-major fp32
__global__ void transpose_cvt(const float* __restrict__ in, u16* __restrict__ out, int K, int N) {
  __shared__ float tile[32][33];
  const int bn = blockIdx.x * 32, bk = blockIdx.y * 32;
  const int tx = threadIdx.x, ty = threadIdx.y;  // 32 x 8
#pragma unroll
  for (int i = 0; i < 32; i += 8)
    tile[ty + i][tx] = in[(size_t)(bk + ty + i) * N + bn + tx];
  __syncthreads();
#pragma unroll
  for (int i = 0; i < 32; i += 8)
    out[(size_t)(bn + ty + i) * K + bk + tx] = f2bf(tile[tx][ty + i]);
}

// fp32 -> bf16, 8 elements per thread-iter (pure BW)
__global__ void cvt_bf16_kernel(const float* __restrict__ in, u16* __restrict__ out, long n8) {
  long i = (long)blockIdx.x * blockDim.x + threadIdx.x;
  const long stride = (long)gridDim.x * blockDim.x;
  for (; i < n8; i += stride) {
    floatx4 a = ((const floatx4*)in)[2 * i], b = ((const floatx4*)in)[2 * i + 1];
    uintx4 o;
    o.x = (unsigned)f2bf(a.x) | ((unsigned)f2bf(a.y) << 16);
    o.y = (unsigned)f2bf(a.z) | ((unsigned)f2bf(a.w) << 16);
    o.z = (unsigned)f2bf(b.x) | ((unsigned)f2bf(b.y) << 16);
    o.w = (unsigned)f2bf(b.z) | ((unsigned)f2bf(b.w) << 16);
    ((uintx4*)out)[i] = o;
  }
}

__device__ __forceinline__ void gld16(const void* g, void* l) {
  __builtin_amdgcn_global_load_lds((const __attribute__((address_space(1))) void*)g,
                                   (__attribute__((address_space(3))) void*)l, 16, 0, 0);
}

template <int LN>
__device__ __forceinline__ void vwait() {
  if constexpr (LN == 0) asm volatile("s_waitcnt vmcnt(0)" ::: "memory");
  else if constexpr (LN == 8) asm volatile("s_waitcnt vmcnt(8)" ::: "memory");
}

// ===== R16-verified: 128x128 GEMM (C = act @ wt^T), BK=64 double-burst, =====
// ===== 64 KB LDS, 4-wave blocks, 2 blocks/CU. All operands bf16.        =====
// Window: {stage(h+1) 32KB -> vwait<8> -> BAR -> 8 reads k0 + 8 reads k1 ->
//  lgkmcnt(8) -> 16 MFMA -> lgkmcnt(0) -> 16 MFMA -> BAR}.
// Half layout: granule (r,q) at slot r*8 + (q ^ (r&7)); kc=1 = kc=0 ^ 32.
template <int K, int EPI>
__global__ __launch_bounds__(256, 2) void gemm64(const u16* __restrict__ act,
                                                 const u16* __restrict__ wt,
                                                 void* __restrict__ Cout, int N, int nbn) {
  constexpr int H = K / 64;
  constexpr int BUF = 16384;  // u16: A 8192 + W 8192 (32 KB); x2 = 64 KB
  __shared__ u16 lds[2 * BUF];
  u16* L = lds;
  const int tid = threadIdx.x, lane = tid & 63, wv = tid >> 6;  // 4 waves
  const int l15 = lane & 15, g = lane >> 4;
  const int wvm = wv >> 1, wvn = wv & 1;  // 2 x 2; wave owns 64m x 64n
  const int nwg = gridDim.x, o = blockIdx.x;
  const int sw = (o & 7) * (nwg >> 3) + (o >> 3);  // XCD swizzle (nwg % 8 == 0)
  const int bm = sw / nbn, bn = sw % nbn;
  const size_t am0 = (size_t)bm * 128;
  const size_t wn0 = (size_t)bn * 128;

  // fragment offsets for kc=0 (u16 units within a buffer); kc=1 = ^32
  int afo[4], wfo[4];
#pragma unroll
  for (int mt = 0; mt < 4; ++mt) {
    const int r = wvm * 64 + mt * 16 + l15;
    afo[mt] = (r * 8 + (g ^ (r & 7))) * 8;
  }
#pragma unroll
  for (int nt = 0; nt < 4; ++nt) {
    const int r = wvn * 64 + nt * 16 + l15;
    wfo[nt] = 8192 + (r * 8 + (g ^ (r & 7))) * 8;
  }

  // staging: thread fills slots s = j*256 + tid (j=0..3); granule (s>>3, (s&7)^(r&7))
  int rS[4], qS[4];
#pragma unroll
  for (int j = 0; j < 4; ++j) {
    const int s = j * 256 + tid;
    rS[j] = s >> 3;
    qS[j] = (s & 7) ^ (rS[j] & 7);
  }
  const u16* asrc = act + am0 * K;
  const u16* wsrc = wt + wn0 * K;

#define STG_W(hh)                                                                   \
  { _Pragma("unroll") for (int j = 0; j < 4; ++j)                                   \
      gld16(wsrc + (size_t)rS[j] * K + qS[j] * 8 + (hh) * 64,                       \
            L + ((hh) & 1) * BUF + 8192 + (j * 256 + tid) * 8); }
#define STG_A(hh)                                                                   \
  { _Pragma("unroll") for (int j = 0; j < 4; ++j)                                   \
      gld16(asrc + (size_t)rS[j] * K + qS[j] * 8 + (hh) * 64,                       \
            L + ((hh) & 1) * BUF + (j * 256 + tid) * 8); }

  floatx4 acc[4][4];
  const floatx4 z4 = {0.f, 0.f, 0.f, 0.f};
#pragma unroll
  for (int nt = 0; nt < 4; ++nt)
#pragma unroll
    for (int mt = 0; mt < 4; ++mt) acc[nt][mt] = z4;

  // prologue: stage step 0
  STG_A(0) STG_W(0)

#pragma unroll 1
  for (int h = 0; h < H; ++h) {
    const int cb = (h & 1) * BUF;
    if (h + 1 < H) {
      STG_A(h + 1) STG_W(h + 1) vwait<8>();
    } else {
      vwait<0>();
    }
    BAR();
    short8 a0 = *(const short8*)(L + cb + afo[0]);
    short8 a1 = *(const short8*)(L + cb + afo[1]);
    short8 a2 = *(const short8*)(L + cb + afo[2]);
    short8 a3 = *(const short8*)(L + cb + afo[3]);
    short8 w0 = *(const short8*)(L + cb + wfo[0]);
    short8 w1 = *(const short8*)(L + cb + wfo[1]);
    short8 w2 = *(const short8*)(L + cb + wfo[2]);
    short8 w3 = *(const short8*)(L + cb + wfo[3]);
    short8 b0 = *(const short8*)(L + cb + (afo[0] ^ 32));
    short8 b1 = *(const short8*)(L + cb + (afo[1] ^ 32));
    short8 b2 = *(const short8*)(L + cb + (afo[2] ^ 32));
    short8 b3 = *(const short8*)(L + cb + (afo[3] ^ 32));
    short8 x0 = *(const short8*)(L + cb + (wfo[0] ^ 32));
    short8 x1 = *(const short8*)(L + cb + (wfo[1] ^ 32));
    short8 x2 = *(const short8*)(L + cb + (wfo[2] ^ 32));
    short8 x3 = *(const short8*)(L + cb + (wfo[3] ^ 32));
    LGKM8();
    __builtin_amdgcn_s_setprio(1);
    acc[0][0] = MFMA(w0, a0, acc[0][0]);
    acc[0][1] = MFMA(w0, a1, acc[0][1]);
    acc[0][2] = MFMA(w0, a2, acc[0][2]);
    acc[0][3] = MFMA(w0, a3, acc[0][3]);
    acc[1][0] = MFMA(w1, a0, acc[1][0]);
    acc[1][1] = MFMA(w1, a1, acc[1][1]);
    acc[1][2] = MFMA(w1, a2, acc[1][2]);
    acc[1][3] = MFMA(w1, a3, acc[1][3]);
    acc[2][0] = MFMA(w2, a0, acc[2][0]);
    acc[2][1] = MFMA(w2, a1, acc[2][1]);
    acc[2][2] = MFMA(w2, a2, acc[2][2]);
    acc[2][3] = MFMA(w2, a3, acc[2][3]);
    acc[3][0] = MFMA(w3, a0, acc[3][0]);
    acc[3][1] = MFMA(w3, a1, acc[3][1]);
    acc[3][2] = MFMA(w3, a2, acc[3][2]);
    acc[3][3] = MFMA(w3, a3, acc[3][3]);
    LGKM0();
    acc[0][0] = MFMA(x0, b0, acc[0][0]);
    acc[0][1] = MFMA(x0, b1, acc[0][1]);
    acc[0][2] = MFMA(x0, b2, acc[0][2]);
    acc[0][3] = MFMA(x0, b3, acc[0][3]);
    acc[1][0] = MFMA(x1, b0, acc[1][0]);
    acc[1][1] = MFMA(x1, b1, acc[1][1]);
    acc[1][2] = MFMA(x1, b2, acc[1][2]);
    acc[1][3] = MFMA(x1, b3, acc[1][3]);
    acc[2][0] = MFMA(x2, b0, acc[2][0]);
    acc[2][1] = MFMA(x2, b1, acc[2][1]);
    acc[2][2] = MFMA(x2, b2, acc[2][2]);
    acc[2][3] = MFMA(x2, b3, acc[2][3]);
    acc[3][0] = MFMA(x3, b0, acc[3][0]);
    acc[3][1] = MFMA(x3, b1, acc[3][1]);
    acc[3][2] = MFMA(x3, b2, acc[3][2]);
    acc[3][3] = MFMA(x3, b3, acc[3][3]);
    __builtin_amdgcn_s_setprio(0);
    BAR();
  }
#undef STG_W
#undef STG_A

  __syncthreads();  // loop drained; LDS reusable

  if constexpr (EPI == 0) {
    // softplus -> bf16 C (128x128 = 32 KB) via LDS transpose, one pass
    u16* cl = L;
#pragma unroll
    for (int nt = 0; nt < 4; ++nt)
#pragma unroll
      for (int mt = 0; mt < 4; ++mt) {
        const int m = wvm * 64 + mt * 16 + l15;
        const int n0 = wvn * 64 + nt * 16 + g * 4;
        const int j = n0 >> 3, hh = (n0 >> 2) & 1;
        uintx2 pk;
        pk.x = pack_sp(acc[nt][mt].x, acc[nt][mt].y);
        pk.y = pack_sp(acc[nt][mt].z, acc[nt][mt].w);
        *(uintx2*)(cl + m * 128 + ((j ^ (m & 7)) << 3) + (hh << 2)) = pk;
      }
    __syncthreads();
    u16* outp = (u16*)Cout;
#pragma unroll
    for (int i = 0; i < 8; ++i) {
      const int c = i * 256 + tid;  // 16B chunk; 16/row, 128 rows
      const int m = c >> 4, j = c & 15;
      uintx4 v = *(const uintx4*)(cl + m * 128 + ((j ^ (m & 7)) << 3));
      *(uintx4*)(outp + (am0 + m) * N + wn0 + j * 8) = v;
    }
  } else {
    // fp32 C in two 64-row passes (32 KB each)
    float* cf = (float*)L;
#pragma unroll
    for (int q = 0; q < 2; ++q) {
      if (q) __syncthreads();
      if (wvm == q) {
#pragma unroll
        for (int nt = 0; nt < 4; ++nt)
#pragma unroll
          for (int mt = 0; mt < 4; ++mt) {
            const int m = mt * 16 + l15;  // 0..63
            const int p = (wvn * 64 + nt * 16 + g * 4) >> 1;  // even 2-float slot
            *(floatx4*)(cf + m * 128 + ((p ^ ((m & 7) << 1)) << 1)) = acc[nt][mt];
          }
      }
      __syncthreads();
      float* outp = (float*)Cout;
#pragma unroll
      for (int i = 0; i < 8; ++i) {
        const int c = i * 256 + tid;  // 16B chunk; 32/row, 64 rows
        const int m = c >> 5, cc = c & 31;
        const int p = cc * 2;
        floatx4 v = *(const floatx4*)(cf + m * 128 + ((p ^ ((m & 7) << 1)) << 1));
        *(floatx4*)(outp + (am0 + q * 64 + m) * N + wn0 + cc * 4) = v;
      }
    }
  }
}

// ---------------- fallback: R1 fused kernel (ws too small) ----------------
__global__ __launch_bounds__(512, 2) void mlp3_fused(const float* __restrict__ x,
                                                     const u16* __restrict__ w1t,
                                                     const u16* __restrict__ w2t,
                                                     const u16* __restrict__ w3t,
                                                     float* __restrict__ out) {
  __shared__ u16 h1s[64 * 1024];
  __shared__ u16 xs[64 * 256];
  const int tid = threadIdx.x, lane = tid & 63, wv = tid >> 6;
  const int l15 = lane & 15, g = lane >> 4;
  const size_t m0 = (size_t)blockIdx.x * 64;
  const floatx4 z4 = {0.f, 0.f, 0.f, 0.f};
  {
    const float* xp = x + m0 * 256;
#pragma unroll
    for (int r = 0; r < 8; ++r) {
      int idx4 = r * 512 + tid;
      int m = idx4 >> 6, k = (idx4 & 63) << 2;
      floatx4 v = *(const floatx4*)(xp + m * 256 + k);
      uintx2 pk;
      pk.x = (unsigned)f2bf(v.x) | ((unsigned)f2bf(v.y) << 16);
      pk.y = (unsigned)f2bf(v.z) | ((unsigned)f2bf(v.w) << 16);
      *(uintx2*)(xs + ((m * 256 + k) ^ ((m & 7) << 3))) = pk;
    }
  }
  __syncthreads();
#pragma unroll 1
  for (int c = 0; c < 4; ++c) {
    floatx4 acc[2][4];
#pragma unroll
    for (int t = 0; t < 2; ++t)
#pragma unroll
      for (int mt = 0; mt < 4; ++mt) acc[t][mt] = z4;
    const u16* p0 = w1t + (size_t)(c * 256 + wv * 32 + l15) * 256;
#pragma unroll
    for (int ks = 0; ks < 8; ++ks) {
      const int k = ks * 32 + g * 8;
      short8 a0 = *(const short8*)(p0 + k);
      short8 a1 = *(const short8*)(p0 + 16 * 256 + k);
      short8 b0 = *(const short8*)(xs + (((0 * 16 + l15) * 256 + k) ^ ((l15 & 7) << 3)));
      short8 b1 = *(const short8*)(xs + (((1 * 16 + l15) * 256 + k) ^ ((l15 & 7) << 3)));
      short8 b2 = *(const short8*)(xs + (((2 * 16 + l15) * 256 + k) ^ ((l15 & 7) << 3)));
      short8 b3 = *(const short8*)(xs + (((3 * 16 + l15) * 256 + k) ^ ((l15 & 7) << 3)));
      acc[0][0] = MFMA(a0, b0, acc[0][0]); acc[0][1] = MFMA(a0, b1, acc[0][1]);
      acc[0][2] = MFMA(a0, b2, acc[0][2]); acc[0][3] = MFMA(a0, b3, acc[0][3]);
      acc[1][0] = MFMA(a1, b0, acc[1][0]); acc[1][1] = MFMA(a1, b1, acc[1][1]);
      acc[1][2] = MFMA(a1, b2, acc[1][2]); acc[1][3] = MFMA(a1, b3, acc[1][3]);
    }
#pragma unroll
    for (int t = 0; t < 2; ++t)
#pragma unroll
      for (int mt = 0; mt < 4; ++mt) {
        const int n1 = c * 256 + wv * 32 + t * 16 + g * 4;
        const int m = mt * 16 + l15;
        uintx2 pk;
        pk.x = pack_sp(acc[t][mt].x, acc[t][mt].y);
        pk.y = pack_sp(acc[t][mt].z, acc[t][mt].w);
        *(uintx2*)(h1s + ((m * 1024 + n1) ^ ((m & 7) << 3))) = pk;
      }
  }
  __syncthreads();
  floatx4 acc3[2][4];
#pragma unroll
  for (int t = 0; t < 2; ++t)
#pragma unroll
    for (int mt = 0; mt < 4; ++mt) acc3[t][mt] = z4;
#pragma unroll 1
  for (int c2 = 0; c2 < 4; ++c2) {
    floatx4 acc2[2][4];
#pragma unroll
    for (int t = 0; t < 2; ++t)
#pragma unroll
      for (int mt = 0; mt < 4; ++mt) acc2[t][mt] = z4;
    {
      const u16* p0 = w2t + (size_t)(c2 * 256 + wv * 32 + l15) * 1024;
#pragma unroll 4
      for (int ks = 0; ks < 32; ++ks) {
        const int k = ks * 32 + g * 8;
        short8 a0 = *(const short8*)(p0 + k);
        short8 a1 = *(const short8*)(p0 + 16 * 1024 + k);
        short8 b0 = *(const short8*)(h1s + (((0 * 16 + l15) * 1024 + k) ^ ((l15 & 7) << 3)));
        short8 b1 = *(const short8*)(h1s + (((1 * 16 + l15) * 1024 + k) ^ ((l15 & 7) << 3)));
        short8 b2 = *(const short8*)(h1s + (((2 * 16 + l15) * 1024 + k) ^ ((l15 & 7) << 3)));
        short8 b3 = *(const short8*)(h1s + (((3 * 16 + l15) * 1024 + k) ^ ((l15 & 7) << 3)));
        acc2[0][0] = MFMA(a0, b0, acc2[0][0]); acc2[0][1] = MFMA(a0, b1, acc2[0][1]);
        acc2[0][2] = MFMA(a0, b2, acc2[0][2]); acc2[0][3] = MFMA(a0, b3, acc2[0][3]);
        acc2[1][0] = MFMA(a1, b0, acc2[1][0]); acc2[1][1] = MFMA(a1, b1, acc2[1][1]);
        acc2[1][2] = MFMA(a1, b2, acc2[1][2]); acc2[1][3] = MFMA(a1, b3, acc2[1][3]);
      }
    }
    __syncthreads();
#pragma unroll
    for (int t = 0; t < 2; ++t)
#pragma unroll
      for (int mt = 0; mt < 4; ++mt) {
        const int n2l = wv * 32 + t * 16 + g * 4;
        const int m = mt * 16 + l15;
        uintx2 pk;
        pk.x = pack_sp(acc2[t][mt].x, acc2[t][mt].y);
        pk.y = pack_sp(acc2[t][mt].z, acc2[t][mt].w);
        *(uintx2*)(xs + ((m * 256 + n2l) ^ ((m & 7) << 3))) = pk;
      }
    __syncthreads();
    {
      const u16* p0 = w3t + (size_t)(wv * 32 + l15) * 1024 + c2 * 256;
#pragma unroll
      for (int ks = 0; ks < 8; ++ks) {
        const int k = ks * 32 + g * 8;
        short8 a0 = *(const short8*)(p0 + k);
        short8 a1 = *(const short8*)(p0 + 16 * 1024 + k);
        short8 b0 = *(const short8*)(xs + (((0 * 16 + l15) * 256 + k) ^ ((l15 & 7) << 3)));
        short8 b1 = *(const short8*)(xs + (((1 * 16 + l15) * 256 + k) ^ ((l15 & 7) << 3)));
        short8 b2 = *(const short8*)(xs + (((2 * 16 + l15) * 256 + k) ^ ((l15 & 7) << 3)));
        short8 b3 = *(const short8*)(xs + (((3 * 16 + l15) * 256 + k) ^ ((l15 & 7) << 3)));
        acc3[0][0] = MFMA(a0, b0, acc3[0][0]); acc3[0][1] = MFMA(a0, b1, acc3[0][1]);
        acc3[0][2] = MFMA(a0, b2, acc3[0][2]); acc3[0][3] = MFMA(a0, b3, acc3[0][3]);
        acc3[1][0] = MFMA(a1, b0, acc3[1][0]); acc3[1][1] = MFMA(a1, b1, acc3[1][1]);
        acc3[1][2] = MFMA(a1, b2, acc3[1][2]); acc3[1][3] = MFMA(a1, b3, acc3[1][3]);
      }
    }
  }
#pragma unroll
  for (int t = 0; t < 2; ++t)
#pragma unroll
    for (int mt = 0; mt < 4; ++mt) {
      const int n3 = wv * 32 + t * 16 + g * 4;
      const int m = mt * 16 + l15;
      *(floatx4*)(out + (m0 + m) * 256 + n3) = acc3[t][mt];
    }
}

extern "C" void kernel_launch(void* const* d_in, const int* in_sizes, int n_in,
                              void* d_out, int out_size, void* d_ws, size_t ws_size,
                              hipStream_t stream) {
  const float* x = (const float*)d_in[0];
  const float* w1 = (const float*)d_in[1];
  const float* w2 = (const float*)d_in[2];
  const float* w3 = (const float*)d_in[3];
  float* out = (float*)d_out;
  const size_t M = 131072;

  u16* w1t = (u16*)d_ws;                      // [1024][256]
  u16* w2t = w1t + 1024 * 256;                // [1024][1024]
  u16* w3t = w2t + 1024 * 1024;               // [256][1024]
  u16* bufA = w3t + 256 * 1024;               // h1: CM x 1024 bf16
  const size_t weights_el = 1024 * 256 + 1024 * 1024 + 256 * 1024;

  size_t CM = 0;
  const size_t cands[4] = {32768, 16384, 8192, 4096};
  for (int i = 0; i < 4; ++i) {
    size_t need = (weights_el + 2 * cands[i] * 1024) * sizeof(u16);
    if (ws_size >= need) { CM = cands[i]; break; }
  }

  dim3 tb(32, 8);
  transpose_cvt<<<dim3(32, 8), tb, 0, stream>>>(w1, w1t, 256, 1024);
  transpose_cvt<<<dim3(32, 32), tb, 0, stream>>>(w2, w2t, 1024, 1024);
  transpose_cvt<<<dim3(8, 32), tb, 0, stream>>>(w3, w3t, 1024, 256);

  if (CM) {
    u16* bufB = bufA + CM * 1024;
    const int nchunk = (int)(M / CM);
    for (int ci = 0; ci < nchunk; ++ci) {
      const float* xc = x + (size_t)ci * CM * 256;
      float* oc = out + (size_t)ci * CM * 256;
      // xbf16 lives in bufB's prefix (CM*256 u16); bufB is dead until G2 writes it,
      // and G2 (which overwrites the prefix) only runs after G1 has consumed it.
      cvt_bf16_kernel<<<2048, 256, 0, stream>>>(xc, bufB, (long)(CM * 32));
      gemm64<256, 0><<<(int)(CM / 128) * 8, 256, 0, stream>>>(bufB, w1t, bufA, 1024, 8);
      gemm64<1024, 0><<<(int)(CM / 128) * 8, 256, 0, stream>>>(bufA, w2t, bufB, 1024, 8);
      gemm64<1024, 1><<<(int)(CM / 128) * 2, 256, 0, stream>>>(bufB, w3t, oc, 256, 2);
    }
  } else {
    mlp3_fused<<<M / 64, 512, 0, stream>>>(x, w1t, w2t, w3t, out);
  }
}

// Round 19
// 623.656 us; speedup vs baseline: 1.0632x; 1.0107x over previous
//
#include <hip/hip_runtime.h>

typedef __attribute__((ext_vector_type(8))) short short8;
typedef __attribute__((ext_vector_type(4))) float floatx4;
typedef __attribute__((ext_vector_type(2))) unsigned int uintx2;
typedef __attribute__((ext_vector_type(4))) unsigned int uintx4;
typedef unsigned short u16;

#define MFMA(a, b, c) __builtin_amdgcn_mfma_f32_16x16x32_bf16((a), (b), (c), 0, 0, 0)
#define BAR() do { asm volatile("" ::: "memory"); __builtin_amdgcn_s_barrier(); \
                   asm volatile("" ::: "memory"); } while (0)
#define LGKM0() asm volatile("s_waitcnt lgkmcnt(0)" ::: "memory")
#define LGKM8() asm volatile("s_waitcnt lgkmcnt(8)" ::: "memory")

__device__ __forceinline__ u16 f2bf(float f) {
  unsigned int u = __builtin_bit_cast(unsigned int, f);
  u += ((u >> 16) & 1u) + 0x7fffu;
  return (u16)(u >> 16);
}

__device__ __forceinline__ float softplus_f(float v) {
  float a = __builtin_fabsf(v);
  float e = __expf(-a);
  float l = __logf(1.0f + e);
  return __builtin_fmaxf(v, 0.0f) + l;
}

__device__ __forceinline__ unsigned int pack_sp(float lo, float hi) {
  return (unsigned int)f2bf(softplus_f(lo)) | ((unsigned int)f2bf(softplus_f(hi)) << 16);
}

// ---- fused weight prep: one launch transposes W1, W2, W3 ----
// out[n*K + k] = bf16(in[k*N + n]). Block b covers a 32x32 tile of one matrix.
__global__ void prep_weights(const float* __restrict__ w1, const float* __restrict__ w2,
                             const float* __restrict__ w3, u16* __restrict__ w1t,
                             u16* __restrict__ w2t, u16* __restrict__ w3t) {
  __shared__ float tile[32][33];
  const int b = blockIdx.x;
  const float* in;
  u16* out;
  int K, N, bx, by;
  if (b < 256) {           // W1: 256x1024 -> w1t[1024][256]; 32x8 tiles
    in = w1; out = w1t; K = 256; N = 1024; bx = b & 31; by = b >> 5;
  } else if (b < 256 + 1024) {  // W2: 1024x1024 -> w2t[1024][1024]; 32x32 tiles
    const int c = b - 256;
    in = w2; out = w2t; K = 1024; N = 1024; bx = c & 31; by = c >> 5;
  } else {                 // W3: 1024x256 -> w3t[256][1024]; 8x32 tiles
    const int c = b - 256 - 1024;
    in = w3; out = w3t; K = 1024; N = 256; bx = c & 7; by = c >> 3;
  }
  const int bn = bx * 32, bk = by * 32;
  const int tx = threadIdx.x, ty = threadIdx.y;  // 32 x 8
#pragma unroll
  for (int i = 0; i < 32; i += 8)
    tile[ty + i][tx] = in[(size_t)(bk + ty + i) * N + bn + tx];
  __syncthreads();
#pragma unroll
  for (int i = 0; i < 32; i += 8)
    out[(size_t)(bn + ty + i) * K + bk + tx] = f2bf(tile[tx][ty + i]);
}

// fp32 -> bf16, 8 elements per thread-iter (pure BW)
__global__ void cvt_bf16_kernel(const float* __restrict__ in, u16* __restrict__ out, long n8) {
  long i = (long)blockIdx.x * blockDim.x + threadIdx.x;
  const long stride = (long)gridDim.x * blockDim.x;
  for (; i < n8; i += stride) {
    floatx4 a = ((const floatx4*)in)[2 * i], b = ((const floatx4*)in)[2 * i + 1];
    uintx4 o;
    o.x = (unsigned)f2bf(a.x) | ((unsigned)f2bf(a.y) << 16);
    o.y = (unsigned)f2bf(a.z) | ((unsigned)f2bf(a.w) << 16);
    o.z = (unsigned)f2bf(b.x) | ((unsigned)f2bf(b.y) << 16);
    o.w = (unsigned)f2bf(b.z) | ((unsigned)f2bf(b.w) << 16);
    ((uintx4*)out)[i] = o;
  }
}

__device__ __forceinline__ void gld16(const void* g, void* l) {
  __builtin_amdgcn_global_load_lds((const __attribute__((address_space(1))) void*)g,
                                   (__attribute__((address_space(3))) void*)l, 16, 0, 0);
}

template <int LN>
__device__ __forceinline__ void vwait() {
  if constexpr (LN == 0) asm volatile("s_waitcnt vmcnt(0)" ::: "memory");
  else if constexpr (LN == 8) asm volatile("s_waitcnt vmcnt(8)" ::: "memory");
}

// ===== R16-verified: 128x128 GEMM (C = act @ wt^T), BK=64 double-burst, =====
// ===== 64 KB LDS, 4-wave blocks, 2 blocks/CU. All operands bf16.        =====
template <int K, int EPI>
__global__ __launch_bounds__(256, 2) void gemm64(const u16* __restrict__ act,
                                                 const u16* __restrict__ wt,
                                                 void* __restrict__ Cout, int N, int nbn) {
  constexpr int H = K / 64;
  constexpr int BUF = 16384;  // u16: A 8192 + W 8192 (32 KB); x2 = 64 KB
  __shared__ u16 lds[2 * BUF];
  u16* L = lds;
  const int tid = threadIdx.x, lane = tid & 63, wv = tid >> 6;  // 4 waves
  const int l15 = lane & 15, g = lane >> 4;
  const int wvm = wv >> 1, wvn = wv & 1;  // 2 x 2; wave owns 64m x 64n
  const int nwg = gridDim.x, o = blockIdx.x;
  const int sw = (o & 7) * (nwg >> 3) + (o >> 3);  // XCD swizzle (nwg % 8 == 0)
  const int bm = sw / nbn, bn = sw % nbn;
  const size_t am0 = (size_t)bm * 128;
  const size_t wn0 = (size_t)bn * 128;

  int afo[4], wfo[4];
#pragma unroll
  for (int mt = 0; mt < 4; ++mt) {
    const int r = wvm * 64 + mt * 16 + l15;
    afo[mt] = (r * 8 + (g ^ (r & 7))) * 8;
  }
#pragma unroll
  for (int nt = 0; nt < 4; ++nt) {
    const int r = wvn * 64 + nt * 16 + l15;
    wfo[nt] = 8192 + (r * 8 + (g ^ (r & 7))) * 8;
  }

  int rS[4], qS[4];
#pragma unroll
  for (int j = 0; j < 4; ++j) {
    const int s = j * 256 + tid;
    rS[j] = s >> 3;
    qS[j] = (s & 7) ^ (rS[j] & 7);
  }
  const u16* asrc = act + am0 * K;
  const u16* wsrc = wt + wn0 * K;

#define STG_W(hh)                                                                   \
  { _Pragma("unroll") for (int j = 0; j < 4; ++j)                                   \
      gld16(wsrc + (size_t)rS[j] * K + qS[j] * 8 + (hh) * 64,                       \
            L + ((hh) & 1) * BUF + 8192 + (j * 256 + tid) * 8); }
#define STG_A(hh)                                                                   \
  { _Pragma("unroll") for (int j = 0; j < 4; ++j)                                   \
      gld16(asrc + (size_t)rS[j] * K + qS[j] * 8 + (hh) * 64,                       \
            L + ((hh) & 1) * BUF + (j * 256 + tid) * 8); }

  floatx4 acc[4][4];
  const floatx4 z4 = {0.f, 0.f, 0.f, 0.f};
#pragma unroll
  for (int nt = 0; nt < 4; ++nt)
#pragma unroll
    for (int mt = 0; mt < 4; ++mt) acc[nt][mt] = z4;

  STG_A(0) STG_W(0)

#pragma unroll 1
  for (int h = 0; h < H; ++h) {
    const int cb = (h & 1) * BUF;
    if (h + 1 < H) {
      STG_A(h + 1) STG_W(h + 1) vwait<8>();
    } else {
      vwait<0>();
    }
    BAR();
    short8 a0 = *(const short8*)(L + cb + afo[0]);
    short8 a1 = *(const short8*)(L + cb + afo[1]);
    short8 a2 = *(const short8*)(L + cb + afo[2]);
    short8 a3 = *(const short8*)(L + cb + afo[3]);
    short8 w0 = *(const short8*)(L + cb + wfo[0]);
    short8 w1 = *(const short8*)(L + cb + wfo[1]);
    short8 w2 = *(const short8*)(L + cb + wfo[2]);
    short8 w3 = *(const short8*)(L + cb + wfo[3]);
    short8 b0 = *(const short8*)(L + cb + (afo[0] ^ 32));
    short8 b1 = *(const short8*)(L + cb + (afo[1] ^ 32));
    short8 b2 = *(const short8*)(L + cb + (afo[2] ^ 32));
    short8 b3 = *(const short8*)(L + cb + (afo[3] ^ 32));
    short8 x0 = *(const short8*)(L + cb + (wfo[0] ^ 32));
    short8 x1 = *(const short8*)(L + cb + (wfo[1] ^ 32));
    short8 x2 = *(const short8*)(L + cb + (wfo[2] ^ 32));
    short8 x3 = *(const short8*)(L + cb + (wfo[3] ^ 32));
    LGKM8();
    __builtin_amdgcn_s_setprio(1);
    acc[0][0] = MFMA(w0, a0, acc[0][0]);
    acc[0][1] = MFMA(w0, a1, acc[0][1]);
    acc[0][2] = MFMA(w0, a2, acc[0][2]);
    acc[0][3] = MFMA(w0, a3, acc[0][3]);
    acc[1][0] = MFMA(w1, a0, acc[1][0]);
    acc[1][1] = MFMA(w1, a1, acc[1][1]);
    acc[1][2] = MFMA(w1, a2, acc[1][2]);
    acc[1][3] = MFMA(w1, a3, acc[1][3]);
    acc[2][0] = MFMA(w2, a0, acc[2][0]);
    acc[2][1] = MFMA(w2, a1, acc[2][1]);
    acc[2][2] = MFMA(w2, a2, acc[2][2]);
    acc[2][3] = MFMA(w2, a3, acc[2][3]);
    acc[3][0] = MFMA(w3, a0, acc[3][0]);
    acc[3][1] = MFMA(w3, a1, acc[3][1]);
    acc[3][2] = MFMA(w3, a2, acc[3][2]);
    acc[3][3] = MFMA(w3, a3, acc[3][3]);
    LGKM0();
    acc[0][0] = MFMA(x0, b0, acc[0][0]);
    acc[0][1] = MFMA(x0, b1, acc[0][1]);
    acc[0][2] = MFMA(x0, b2, acc[0][2]);
    acc[0][3] = MFMA(x0, b3, acc[0][3]);
    acc[1][0] = MFMA(x1, b0, acc[1][0]);
    acc[1][1] = MFMA(x1, b1, acc[1][1]);
    acc[1][2] = MFMA(x1, b2, acc[1][2]);
    acc[1][3] = MFMA(x1, b3, acc[1][3]);
    acc[2][0] = MFMA(x2, b0, acc[2][0]);
    acc[2][1] = MFMA(x2, b1, acc[2][1]);
    acc[2][2] = MFMA(x2, b2, acc[2][2]);
    acc[2][3] = MFMA(x2, b3, acc[2][3]);
    acc[3][0] = MFMA(x3, b0, acc[3][0]);
    acc[3][1] = MFMA(x3, b1, acc[3][1]);
    acc[3][2] = MFMA(x3, b2, acc[3][2]);
    acc[3][3] = MFMA(x3, b3, acc[3][3]);
    __builtin_amdgcn_s_setprio(0);
    BAR();
  }
#undef STG_W
#undef STG_A

  __syncthreads();  // loop drained; LDS reusable

  if constexpr (EPI == 0) {
    u16* cl = L;
#pragma unroll
    for (int nt = 0; nt < 4; ++nt)
#pragma unroll
      for (int mt = 0; mt < 4; ++mt) {
        const int m = wvm * 64 + mt * 16 + l15;
        const int n0 = wvn * 64 + nt * 16 + g * 4;
        const int j = n0 >> 3, hh = (n0 >> 2) & 1;
        uintx2 pk;
        pk.x = pack_sp(acc[nt][mt].x, acc[nt][mt].y);
        pk.y = pack_sp(acc[nt][mt].z, acc[nt][mt].w);
        *(uintx2*)(cl + m * 128 + ((j ^ (m & 7)) << 3) + (hh << 2)) = pk;
      }
    __syncthreads();
    u16* outp = (u16*)Cout;
#pragma unroll
    for (int i = 0; i < 8; ++i) {
      const int c = i * 256 + tid;
      const int m = c >> 4, j = c & 15;
      uintx4 v = *(const uintx4*)(cl + m * 128 + ((j ^ (m & 7)) << 3));
      *(uintx4*)(outp + (am0 + m) * N + wn0 + j * 8) = v;
    }
  } else {
    float* cf = (float*)L;
#pragma unroll
    for (int q = 0; q < 2; ++q) {
      if (q) __syncthreads();
      if (wvm == q) {
#pragma unroll
        for (int nt = 0; nt < 4; ++nt)
#pragma unroll
          for (int mt = 0; mt < 4; ++mt) {
            const int m = mt * 16 + l15;
            const int p = (wvn * 64 + nt * 16 + g * 4) >> 1;
            *(floatx4*)(cf + m * 128 + ((p ^ ((m & 7) << 1)) << 1)) = acc[nt][mt];
          }
      }
      __syncthreads();
      float* outp = (float*)Cout;
#pragma unroll
      for (int i = 0; i < 8; ++i) {
        const int c = i * 256 + tid;
        const int m = c >> 5, cc = c & 31;
        const int p = cc * 2;
        floatx4 v = *(const floatx4*)(cf + m * 128 + ((p ^ ((m & 7) << 1)) << 1));
        *(floatx4*)(outp + (am0 + q * 64 + m) * N + wn0 + cc * 4) = v;
      }
    }
  }
}

// ---------------- fallback: R1 fused kernel (ws too small) ----------------
__global__ __launch_bounds__(512, 2) void mlp3_fused(const float* __restrict__ x,
                                                     const u16* __restrict__ w1t,
                                                     const u16* __restrict__ w2t,
                                                     const u16* __restrict__ w3t,
                                                     float* __restrict__ out) {
  __shared__ u16 h1s[64 * 1024];
  __shared__ u16 xs[64 * 256];
  const int tid = threadIdx.x, lane = tid & 63, wv = tid >> 6;
  const int l15 = lane & 15, g = lane >> 4;
  const size_t m0 = (size_t)blockIdx.x * 64;
  const floatx4 z4 = {0.f, 0.f, 0.f, 0.f};
  {
    const float* xp = x + m0 * 256;
#pragma unroll
    for (int r = 0; r < 8; ++r) {
      int idx4 = r * 512 + tid;
      int m = idx4 >> 6, k = (idx4 & 63) << 2;
      floatx4 v = *(const floatx4*)(xp + m * 256 + k);
      uintx2 pk;
      pk.x = (unsigned)f2bf(v.x) | ((unsigned)f2bf(v.y) << 16);
      pk.y = (unsigned)f2bf(v.z) | ((unsigned)f2bf(v.w) << 16);
      *(uintx2*)(xs + ((m * 256 + k) ^ ((m & 7) << 3))) = pk;
    }
  }
  __syncthreads();
#pragma unroll 1
  for (int c = 0; c < 4; ++c) {
    floatx4 acc[2][4];
#pragma unroll
    for (int t = 0; t < 2; ++t)
#pragma unroll
      for (int mt = 0; mt < 4; ++mt) acc[t][mt] = z4;
    const u16* p0 = w1t + (size_t)(c * 256 + wv * 32 + l15) * 256;
#pragma unroll
    for (int ks = 0; ks < 8; ++ks) {
      const int k = ks * 32 + g * 8;
      short8 a0 = *(const short8*)(p0 + k);
      short8 a1 = *(const short8*)(p0 + 16 * 256 + k);
      short8 b0 = *(const short8*)(xs + (((0 * 16 + l15) * 256 + k) ^ ((l15 & 7) << 3)));
      short8 b1 = *(const short8*)(xs + (((1 * 16 + l15) * 256 + k) ^ ((l15 & 7) << 3)));
      short8 b2 = *(const short8*)(xs + (((2 * 16 + l15) * 256 + k) ^ ((l15 & 7) << 3)));
      short8 b3 = *(const short8*)(xs + (((3 * 16 + l15) * 256 + k) ^ ((l15 & 7) << 3)));
      acc[0][0] = MFMA(a0, b0, acc[0][0]); acc[0][1] = MFMA(a0, b1, acc[0][1]);
      acc[0][2] = MFMA(a0, b2, acc[0][2]); acc[0][3] = MFMA(a0, b3, acc[0][3]);
      acc[1][0] = MFMA(a1, b0, acc[1][0]); acc[1][1] = MFMA(a1, b1, acc[1][1]);
      acc[1][2] = MFMA(a1, b2, acc[1][2]); acc[1][3] = MFMA(a1, b3, acc[1][3]);
    }
#pragma unroll
    for (int t = 0; t < 2; ++t)
#pragma unroll
      for (int mt = 0; mt < 4; ++mt) {
        const int n1 = c * 256 + wv * 32 + t * 16 + g * 4;
        const int m = mt * 16 + l15;
        uintx2 pk;
        pk.x = pack_sp(acc[t][mt].x, acc[t][mt].y);
        pk.y = pack_sp(acc[t][mt].z, acc[t][mt].w);
        *(uintx2*)(h1s + ((m * 1024 + n1) ^ ((m & 7) << 3))) = pk;
      }
  }
  __syncthreads();
  floatx4 acc3[2][4];
#pragma unroll
  for (int t = 0; t < 2; ++t)
#pragma unroll
    for (int mt = 0; mt < 4; ++mt) acc3[t][mt] = z4;
#pragma unroll 1
  for (int c2 = 0; c2 < 4; ++c2) {
    floatx4 acc2[2][4];
#pragma unroll
    for (int t = 0; t < 2; ++t)
#pragma unroll
      for (int mt = 0; mt < 4; ++mt) acc2[t][mt] = z4;
    {
      const u16* p0 = w2t + (size_t)(c2 * 256 + wv * 32 + l15) * 1024;
#pragma unroll 4
      for (int ks = 0; ks < 32; ++ks) {
        const int k = ks * 32 + g * 8;
        short8 a0 = *(const short8*)(p0 + k);
        short8 a1 = *(const short8*)(p0 + 16 * 1024 + k);
        short8 b0 = *(const short8*)(h1s + (((0 * 16 + l15) * 1024 + k) ^ ((l15 & 7) << 3)));
        short8 b1 = *(const short8*)(h1s + (((1 * 16 + l15) * 1024 + k) ^ ((l15 & 7) << 3)));
        short8 b2 = *(const short8*)(h1s + (((2 * 16 + l15) * 1024 + k) ^ ((l15 & 7) << 3)));
        short8 b3 = *(const short8*)(h1s + (((3 * 16 + l15) * 1024 + k) ^ ((l15 & 7) << 3)));
        acc2[0][0] = MFMA(a0, b0, acc2[0][0]); acc2[0][1] = MFMA(a0, b1, acc2[0][1]);
        acc2[0][2] = MFMA(a0, b2, acc2[0][2]); acc2[0][3] = MFMA(a0, b3, acc2[0][3]);
        acc2[1][0] = MFMA(a1, b0, acc2[1][0]); acc2[1][1] = MFMA(a1, b1, acc2[1][1]);
        acc2[1][2] = MFMA(a1, b2, acc2[1][2]); acc2[1][3] = MFMA(a1, b3, acc2[1][3]);
      }
    }
    __syncthreads();
#pragma unroll
    for (int t = 0; t < 2; ++t)
#pragma unroll
      for (int mt = 0; mt < 4; ++mt) {
        const int n2l = wv * 32 + t * 16 + g * 4;
        const int m = mt * 16 + l15;
        uintx2 pk;
        pk.x = pack_sp(acc2[t][mt].x, acc2[t][mt].y);
        pk.y = pack_sp(acc2[t][mt].z, acc2[t][mt].w);
        *(uintx2*)(xs + ((m * 256 + n2l) ^ ((m & 7) << 3))) = pk;
      }
    __syncthreads();
    {
      const u16* p0 = w3t + (size_t)(wv * 32 + l15) * 1024 + c2 * 256;
#pragma unroll
      for (int ks = 0; ks < 8; ++ks) {
        const int k = ks * 32 + g * 8;
        short8 a0 = *(const short8*)(p0 + k);
        short8 a1 = *(const short8*)(p0 + 16 * 1024 + k);
        short8 b0 = *(const short8*)(xs + (((0 * 16 + l15) * 256 + k) ^ ((l15 & 7) << 3)));
        short8 b1 = *(const short8*)(xs + (((1 * 16 + l15) * 256 + k) ^ ((l15 & 7) << 3)));
        short8 b2 = *(const short8*)(xs + (((2 * 16 + l15) * 256 + k) ^ ((l15 & 7) << 3)));
        short8 b3 = *(const short8*)(xs + (((3 * 16 + l15) * 256 + k) ^ ((l15 & 7) << 3)));
        acc3[0][0] = MFMA(a0, b0, acc3[0][0]); acc3[0][1] = MFMA(a0, b1, acc3[0][1]);
        acc3[0][2] = MFMA(a0, b2, acc3[0][2]); acc3[0][3] = MFMA(a0, b3, acc3[0][3]);
        acc3[1][0] = MFMA(a1, b0, acc3[1][0]); acc3[1][1] = MFMA(a1, b1, acc3[1][1]);
        acc3[1][2] = MFMA(a1, b2, acc3[1][2]); acc3[1][3] = MFMA(a1, b3, acc3[1][3]);
      }
    }
  }
#pragma unroll
  for (int t = 0; t < 2; ++t)
#pragma unroll
    for (int mt = 0; mt < 4; ++mt) {
      const int n3 = wv * 32 + t * 16 + g * 4;
      const int m = mt * 16 + l15;
      *(floatx4*)(out + (m0 + m) * 256 + n3) = acc3[t][mt];
    }
}

extern "C" void kernel_launch(void* const* d_in, const int* in_sizes, int n_in,
                              void* d_out, int out_size, void* d_ws, size_t ws_size,
                              hipStream_t stream) {
  const float* x = (const float*)d_in[0];
  const float* w1 = (const float*)d_in[1];
  const float* w2 = (const float*)d_in[2];
  const float* w3 = (const float*)d_in[3];
  float* out = (float*)d_out;
  const size_t M = 131072;

  u16* w1t = (u16*)d_ws;                      // [1024][256]
  u16* w2t = w1t + 1024 * 256;                // [1024][1024]
  u16* w3t = w2t + 1024 * 1024;               // [256][1024]
  u16* bufA = w3t + 256 * 1024;               // h1: CM x 1024 bf16
  const size_t weights_el = 1024 * 256 + 1024 * 1024 + 256 * 1024;

  size_t CM = 0;
  const size_t cands[5] = {65536, 32768, 16384, 8192, 4096};
  for (int i = 0; i < 5; ++i) {
    size_t need = (weights_el + 2 * cands[i] * 1024) * sizeof(u16);
    if (ws_size >= need) { CM = cands[i]; break; }
  }

  dim3 tb(32, 8);
  if (CM) {
    prep_weights<<<256 + 1024 + 256, tb, 0, stream>>>(w1, w2, w3, w1t, w2t, w3t);
    u16* bufB = bufA + CM * 1024;
    const int nchunk = (int)(M / CM);
    for (int ci = 0; ci < nchunk; ++ci) {
      const float* xc = x + (size_t)ci * CM * 256;
      float* oc = out + (size_t)ci * CM * 256;
      // xbf16 lives in bufB's prefix (CM*256 u16); bufB is dead until G2 writes it.
      cvt_bf16_kernel<<<2048, 256, 0, stream>>>(xc, bufB, (long)(CM * 32));
      gemm64<256, 0><<<(int)(CM / 128) * 8, 256, 0, stream>>>(bufB, w1t, bufA, 1024, 8);
      gemm64<1024, 0><<<(int)(CM / 128) * 8, 256, 0, stream>>>(bufA, w2t, bufB, 1024, 8);
      gemm64<1024, 1><<<(int)(CM / 128) * 2, 256, 0, stream>>>(bufB, w3t, oc, 256, 2);
    }
  } else {
    u16* w1t2 = (u16*)d_ws;
    prep_weights<<<256 + 1024 + 256, tb, 0, stream>>>(w1, w2, w3, w1t2, w2t, w3t);
    mlp3_fused<<<M / 64, 512, 0, stream>>>(x, w1t2, w2t, w3t, out);
  }
}